// Round 9
// baseline (593.145 us; speedup 1.0000x reference)
//
#include <hip/hip_runtime.h>
#include <hip/hip_bf16.h>

typedef _Float16 f16;
typedef _Float16 f16x8 __attribute__((ext_vector_type(8)));
typedef float f32x4 __attribute__((ext_vector_type(4)));

#define NBATCH 128
#define NTIME  128
#define NKIN   512
#define NUNITS 512
#define NGATE  2048

#define GROUPS 8    // batch groups: grp = bid & 7 (16 rows each)
#define SLOTS  32   // blocks per group: slot = bid >> 3 (16 unit-cols each)
#define GROWS  16   // batch rows per group
#define GUNITS 16   // unit-cols per block (x4 gates = 64 gate-cols)
#define HSZ    (NBATCH * NUNITS)   // one h slot (f16 elems)
#define POISON 0x7C00u             // f16 +inf: impossible as h = o*tanh(c)

static __device__ __forceinline__ float sigmoidf_(float x) {
    return 1.0f / (1.0f + __expf(-x));
}
static __device__ __forceinline__ float tanhf_(float x) {
    float t = __expf(-2.0f * fabsf(x));
    float r = (1.0f - t) / (1.0f + t);
    return copysignf(r, x);
}

static __device__ __forceinline__ f16x8 pack8(float4 a, float4 b) {
    f16x8 r;
    r[0] = (f16)a.x; r[1] = (f16)a.y; r[2] = (f16)a.z; r[3] = (f16)a.w;
    r[4] = (f16)b.x; r[5] = (f16)b.y; r[6] = (f16)b.z; r[7] = (f16)b.w;
    return r;
}

// ---- MALL-coherent (sc0 sc1) ops: bypass L1+L2; device-wide; proven r3/r4/r8 ----
static __device__ __forceinline__ void store_u16_sys(void* p, unsigned short v) {
    asm volatile("global_store_short %0, %1, off sc0 sc1" :: "v"(p), "v"(v) : "memory");
}
static __device__ __forceinline__ void store_16B_sys(void* p, f32x4 v) {
    asm volatile("global_store_dwordx4 %0, %1, off sc0 sc1" :: "v"(p), "v"(v) : "memory");
}
static __device__ __forceinline__ void load4x16_sys(const f16* p, f32x4* a, f32x4* b,
                                                    f32x4* c, f32x4* d) {
    asm volatile("global_load_dwordx4 %0, %4, off sc0 sc1\n\t"
                 "global_load_dwordx4 %1, %5, off sc0 sc1\n\t"
                 "global_load_dwordx4 %2, %6, off sc0 sc1\n\t"
                 "global_load_dwordx4 %3, %7, off sc0 sc1\n\t"
                 "s_waitcnt vmcnt(0)"
                 : "=&v"(*a), "=&v"(*b), "=&v"(*c), "=&v"(*d)
                 : "v"(p), "v"(p + 8), "v"(p + 16), "v"(p + 24) : "memory");
}

// true if no f16 half of the 16B chunk equals the poison pattern
static __device__ __forceinline__ int chunk_clean(f32x4 v) {
#pragma unroll
    for (int i = 0; i < 4; ++i) {
        unsigned u = __float_as_uint(v[i]);
        if ((u & 0xFFFFu) == POISON || (u >> 16) == POISON) return 0;
    }
    return 1;
}

// ---------------- poison init: fill 3 h slots with f16 +inf ----------------
__global__ __launch_bounds__(256)
void k_poison(f16* __restrict__ hsl) {
    f32x4 v;
    const float pf = __uint_as_float((POISON << 16) | POISON);
#pragma unroll
    for (int i = 0; i < 4; ++i) v[i] = pf;
    const size_t i = ((size_t)blockIdx.x * 256 + threadIdx.x) * 8;
    if (i < (size_t)3 * HSZ) *(f32x4*)(hsl + i) = v;
}

// ---------------- transpose: f32 in[512][2048] -> f16 out[2048][512] ----------------
__global__ __launch_bounds__(256)
void k_transpose(const float* __restrict__ in, f16* __restrict__ out) {
    __shared__ f16 tile[64][72];
    const int c0 = blockIdx.x * 64;
    const int r0 = blockIdx.y * 64;
    const int tid = threadIdx.x;
    {
        const int lr = tid >> 2;
        const int lc = (tid & 3) << 4;
        const float* src = in + (size_t)(r0 + lr) * NGATE + c0 + lc;
        float4 v0 = ((const float4*)src)[0];
        float4 v1 = ((const float4*)src)[1];
        float4 v2 = ((const float4*)src)[2];
        float4 v3 = ((const float4*)src)[3];
        *(f16x8*)&tile[lr][lc]     = pack8(v0, v1);
        *(f16x8*)&tile[lr][lc + 8] = pack8(v2, v3);
    }
    __syncthreads();
    {
        const int lc = tid >> 2;
        const int lr = (tid & 3) << 4;
        f16x8 a, b;
#pragma unroll
        for (int i = 0; i < 8; ++i) a[i] = tile[lr + i][lc];
#pragma unroll
        for (int i = 0; i < 8; ++i) b[i] = tile[lr + 8 + i][lc];
        f16* dst = out + (size_t)(c0 + lc) * NKIN + r0 + lr;
        *(f16x8*)dst       = a;
        *(f16x8*)(dst + 8) = b;
    }
}

// ---------------- projection: xz[t][b][g] = x[b][t][:] @ W[:][g] + bias[g] ----------------
__global__ __launch_bounds__(256)
void k_proj(const float* __restrict__ x, const f16* __restrict__ Wt,
            const float* __restrict__ bias, f16* __restrict__ xz) {
    __shared__ f16 As[128][40];
    __shared__ f16 Bs[128][40];
    const int bid = blockIdx.y * gridDim.x + blockIdx.x;   // 0..2047
    const int swz = (bid & 7) * 256 + (bid >> 3);          // XCD-contiguous chunks
    const int nb = swz & 15;
    const int tb = swz >> 4;
    const int n0 = nb * 128;
    const int tid  = threadIdx.x;
    const int lane = tid & 63;
    const int wid  = tid >> 6;
    const int wm = (wid >> 1) * 64;
    const int wn = (wid & 1) * 64;
    const int lm = lane & 15;
    const int lg = lane >> 4;

    f32x4 acc[4][4];
#pragma unroll
    for (int mi = 0; mi < 4; ++mi)
#pragma unroll
        for (int ni = 0; ni < 4; ++ni)
#pragma unroll
            for (int i = 0; i < 4; ++i) acc[mi][ni][i] = 0.0f;

    for (int kt = 0; kt < NKIN; kt += 32) {
        {
            const int brow = tid >> 1;
            const int kq   = (tid & 1) << 4;
            const float* src = x + ((size_t)brow * NTIME + tb) * NKIN + kt + kq;
            float4 v0 = ((const float4*)src)[0];
            float4 v1 = ((const float4*)src)[1];
            float4 v2 = ((const float4*)src)[2];
            float4 v3 = ((const float4*)src)[3];
            *(f16x8*)&As[brow][kq]     = pack8(v0, v1);
            *(f16x8*)&As[brow][kq + 8] = pack8(v2, v3);
        }
        {
            const int nrow = tid >> 1;
            const int kq   = (tid & 1) << 4;
            const f16* src = Wt + (size_t)(n0 + nrow) * NKIN + kt + kq;
            *(f16x8*)&Bs[nrow][kq]     = *(const f16x8*)src;
            *(f16x8*)&Bs[nrow][kq + 8] = *(const f16x8*)(src + 8);
        }
        __syncthreads();
        f16x8 a[4], b[4];
#pragma unroll
        for (int mi = 0; mi < 4; ++mi)
            a[mi] = *(const f16x8*)&As[wm + mi * 16 + lm][lg * 8];
#pragma unroll
        for (int ni = 0; ni < 4; ++ni)
            b[ni] = *(const f16x8*)&Bs[wn + ni * 16 + lm][lg * 8];
#pragma unroll
        for (int mi = 0; mi < 4; ++mi)
#pragma unroll
            for (int ni = 0; ni < 4; ++ni)
                acc[mi][ni] = __builtin_amdgcn_mfma_f32_16x16x32_f16(a[mi], b[ni], acc[mi][ni], 0, 0, 0);
        __syncthreads();
    }
#pragma unroll
    for (int mi = 0; mi < 4; ++mi) {
#pragma unroll
        for (int ni = 0; ni < 4; ++ni) {
            const int col = n0 + wn + ni * 16 + lm;
            const float bv = bias[col];
#pragma unroll
            for (int i = 0; i < 4; ++i) {
                const int brow = wm + mi * 16 + lg * 4 + i;
                xz[((size_t)tb * NBATCH + brow) * NGATE + col] = (f16)(acc[mi][ni][i] + bv);
            }
        }
    }
}

// ---------------- persistent LSTM: U in registers, poll-the-data exchange ----------
// 256 blocks = 8 groups (16 batch rows) x 32 slots (16 unit-cols x 4 gates), STATIC.
// At 1 block/CU = 1 wave/SIMD each wave owns the full VGPR file: its U-slice
// (16 cols x 512 k = 16 B-frags = 64 VGPR) lives in REGISTERS for all 128 steps.
// LDS holds only h rows (A-frags) + gate exchange; 80KB pad forces 1 block/CU.
// h[t] in rotating slot t%3 of a poison-initialized buffer; consumers poll their
// 16B chunks until poison-free (sc0sc1 MALL, proven r8). Depth-3 poison recycle.
__global__ __launch_bounds__(256, 1)
void k_lstm(const f16* __restrict__ xz, const f16* __restrict__ Ut,
            f16* __restrict__ hsl, float* __restrict__ out) {
    __shared__ f16 As[16][512];      // 16 h rows, XOR-swizzled (16KB)
    __shared__ float zs[4][16][17];  // gate exchange (4.25KB)
    __shared__ f16 pad_lds[40960];   // 80KB: forces exactly 1 block/CU
    const int bid = blockIdx.x;
    const int grp  = bid & 7;        // static batch group
    const int slot = bid >> 3;       // static unit slot 0..31
    const int r0 = grp * GROWS;
    const int u0 = slot * GUNITS;
    const int tid  = threadIdx.x;
    const int lane = tid & 63;
    const int g    = tid >> 6;       // wave id == gate (i,f,g,o)
    const int lm = lane & 15;
    const int lg = lane >> 4;

    pad_lds[tid] = (f16)0;           // keep pad alive

    // one-time: load this wave's 16 U B-fragments into registers (64 VGPR).
    // B-frag[ks]: lane (lm,lg) holds Ut[g*512 + u0 + lm][ks*32 + lg*8 .. +8]
    f16x8 bu[16];
    {
        const f16* ub = Ut + ((size_t)(g * NUNITS + u0 + lm)) * NUNITS + lg * 8;
#pragma unroll
        for (int ks = 0; ks < 16; ++ks)
            bu[ks] = *(const f16x8*)(ub + ks * 32);
    }
    // zero As (t=0 uses h=0)
    {
        f32x4 z = {0.f, 0.f, 0.f, 0.f};
        for (int i = tid; i < 16 * 64; i += 256)
            *(f32x4*)&As[i >> 6][(i & 63) * 8] = z;
    }

    const int srow = tid >> 4;       // 0..15
    const int suu  = tid & 15;       // 0..15
    const int gidx = (r0 + srow) * NUNITS + u0 + suu;
    float c_reg = 0.0f;

    // poison chunk vector
    f32x4 pz;
    {
        const float pf = __uint_as_float((POISON << 16) | POISON);
#pragma unroll
        for (int i = 0; i < 4; ++i) pz[i] = pf;
    }

    // xz prefetch (t=0): px[i] = xz[0][r0+lg*4+i][g*512+u0+lm]
    float px[4];
    {
        const f16* xp = xz + ((size_t)(r0 + lg * 4)) * NGATE + g * NUNITS + u0 + lm;
#pragma unroll
        for (int i = 0; i < 4; ++i) px[i] = (float)xp[(size_t)i * NGATE];
    }
    __syncthreads();   // As zero + pad visible before t=0 MFMA

    for (int t = 0; t < NTIME; ++t) {
        const f16* hin = hsl + (size_t)((t + 2) % 3) * HSZ;   // slot of h[t-1]
        f16*      hout = hsl + (size_t)(t % 3) * HSZ;         // slot of h[t]

        if (t > 0) {
            // poll-stage: spin on own 4 chunks (64B of one h row) until poison-free
            {
                const int row = tid >> 4;
                const int seg = tid & 15;
                const f16* src = hin + (size_t)(r0 + row) * NUNITS + seg * 32;
                f32x4 a, b, c, d;
                for (int spin = 0; spin < 65536; ++spin) {
                    load4x16_sys(src, &a, &b, &c, &d);
                    if (chunk_clean(a) && chunk_clean(b) &&
                        chunk_clean(c) && chunk_clean(d)) break;
                }
                const int c0_ = seg * 4;
                *(f32x4*)&As[row][((c0_ + 0) ^ (row & 7)) * 8] = a;
                *(f32x4*)&As[row][((c0_ + 1) ^ (row & 7)) * 8] = b;
                *(f32x4*)&As[row][((c0_ + 2) ^ (row & 7)) * 8] = c;
                *(f32x4*)&As[row][((c0_ + 3) ^ (row & 7)) * 8] = d;
            }
            __syncthreads();
            // recycle: poison own chunk of slot (t+1)%3 (holds h[t-2]; poll success
            // of h[t-1] proves everyone finished reading it). 32 x 16B = 16 rows x 16 units.
            if (tid < 32) {
                f16* ps = hsl + (size_t)((t + 1) % 3) * HSZ
                              + (size_t)(r0 + (tid >> 1)) * NUNITS + u0 + (tid & 1) * 8;
                store_16B_sys(ps, pz);
            }
        }

        // MFMA: wave g computes z[16 rows][16 cols] for its gate.
        // B operands live in registers; only A (h) comes from LDS.
        // 2 independent chains (even/odd ks) halve the dependent-MFMA depth.
        f32x4 accA, accB;
#pragma unroll
        for (int i = 0; i < 4; ++i) { accA[i] = px[i]; accB[i] = 0.f; }
#pragma unroll
        for (int ks = 0; ks < 16; ks += 2) {
            const int ca0 = (((ks + 0) * 4 + lg) ^ (lm & 7)) * 8;
            const int ca1 = (((ks + 1) * 4 + lg) ^ (lm & 7)) * 8;
            f16x8 a0 = *(const f16x8*)&As[lm][ca0];
            f16x8 a1 = *(const f16x8*)&As[lm][ca1];
            accA = __builtin_amdgcn_mfma_f32_16x16x32_f16(a0, bu[ks + 0], accA, 0, 0, 0);
            accB = __builtin_amdgcn_mfma_f32_16x16x32_f16(a1, bu[ks + 1], accB, 0, 0, 0);
        }
        f32x4 acc = accA + accB;

        // prefetch next step's xz (plain cached loads; overlaps rest of step)
        if (t + 1 < NTIME) {
            const f16* xp = xz + ((size_t)(t + 1) * NBATCH + r0 + lg * 4) * NGATE
                               + g * NUNITS + u0 + lm;
#pragma unroll
            for (int i = 0; i < 4; ++i) px[i] = (float)xp[(size_t)i * NGATE];
        }

        // gate exchange: lane (lm,lg) reg i holds z[lg*4+i][lm]
#pragma unroll
        for (int i = 0; i < 4; ++i)
            zs[g][lg * 4 + i][lm] = acc[i];
        __syncthreads();

        // state update: 256 threads = 16 rows x 16 units
        const float zi = zs[0][srow][suu];
        const float zf = zs[1][srow][suu];
        const float zg = zs[2][srow][suu];
        const float zo = zs[3][srow][suu];
        const float iv = sigmoidf_(zi);
        const float fv = sigmoidf_(zf);
        const float gv = tanhf_(zg);
        const float ov = sigmoidf_(zo);
        c_reg = fv * c_reg + iv * gv;
        const float hn = ov * tanhf_(c_reg);

        if (t == NTIME - 1) {
            out[gidx]          = hn;
            out[65536 + gidx]  = hn;
            out[131072 + gidx] = c_reg;
        } else {
            // fire-and-forget h store (wave-coalesced 2B sc0sc1); consumers
            // poll the data itself, so no drain / no flag needed
            union { f16 h; unsigned short u; } cv; cv.h = (f16)hn;
            store_u16_sys(hout + gidx, cv.u);
        }
        __syncthreads();   // protect zs/As from next step's overwrite
    }
}

extern "C" void kernel_launch(void* const* d_in, const int* in_sizes, int n_in,
                              void* d_out, int out_size, void* d_ws, size_t ws_size,
                              hipStream_t stream) {
    const float* x    = (const float*)d_in[0];
    const float* W    = (const float*)d_in[1];
    const float* U    = (const float*)d_in[2];
    const float* bias = (const float*)d_in[3];
    float* out = (float*)d_out;
    char* ws = (char*)d_ws;

    size_t off = 0;
    f16* Wt = (f16*)(ws + off); off += (size_t)NGATE * NKIN * 2;
    f16* Ut = (f16*)(ws + off); off += (size_t)NGATE * NUNITS * 2;
    f16* xz = (f16*)(ws + off); off += (size_t)NTIME * NBATCH * NGATE * 2;  // [t][b][g]
    f16* hsl = (f16*)(ws + off); off += (size_t)3 * HSZ * 2;                // 3 h slots
    if (ws_size < off) return;

    k_poison<<<dim3(96), 256, 0, stream>>>(hsl);
    k_transpose<<<dim3(32, 8), 256, 0, stream>>>(W, Wt);
    k_transpose<<<dim3(32, 8), 256, 0, stream>>>(U, Ut);
    k_proj<<<dim3(16, 128), 256, 0, stream>>>(x, Wt, bias, xz);
    k_lstm<<<dim3(256), 256, 0, stream>>>(xz, Ut, hsl, out);
}

// Round 10
// 537.636 us; speedup vs baseline: 1.1032x; 1.1032x over previous
//
#include <hip/hip_runtime.h>
#include <hip/hip_bf16.h>

typedef _Float16 f16;
typedef _Float16 f16x8 __attribute__((ext_vector_type(8)));
typedef float f32x4 __attribute__((ext_vector_type(4)));

#define NBATCH 128
#define NTIME  128
#define NKIN   512
#define NUNITS 512
#define NGATE  2048

#define GROUPS 8    // batch groups: grp = bid & 7 (16 rows each)
#define SLOTS  32   // blocks per group: slot = bid >> 3 (16 unit-cols each)
#define GROWS  16   // batch rows per group
#define GUNITS 16   // unit-cols per block (x4 gates = 64 gate-cols)
#define HSZ    (NBATCH * NUNITS)   // one h slot (f16 elems)
#define POISON 0x7C00u             // f16 +inf: impossible as h = o*tanh(c)

static __device__ __forceinline__ float sigmoidf_(float x) {
    return 1.0f / (1.0f + __expf(-x));
}
static __device__ __forceinline__ float tanhf_(float x) {
    float t = __expf(-2.0f * fabsf(x));
    float r = (1.0f - t) / (1.0f + t);
    return copysignf(r, x);
}

static __device__ __forceinline__ f16x8 pack8(float4 a, float4 b) {
    f16x8 r;
    r[0] = (f16)a.x; r[1] = (f16)a.y; r[2] = (f16)a.z; r[3] = (f16)a.w;
    r[4] = (f16)b.x; r[5] = (f16)b.y; r[6] = (f16)b.z; r[7] = (f16)b.w;
    return r;
}

// ---- MALL-coherent (sc0 sc1) ops: bypass L1+L2; device-wide; proven r3/r4/r8 ----
static __device__ __forceinline__ void store_u16_sys(void* p, unsigned short v) {
    asm volatile("global_store_short %0, %1, off sc0 sc1" :: "v"(p), "v"(v) : "memory");
}
static __device__ __forceinline__ void store_16B_sys(void* p, f32x4 v) {
    asm volatile("global_store_dwordx4 %0, %1, off sc0 sc1" :: "v"(p), "v"(v) : "memory");
}
static __device__ __forceinline__ void load4x16_sys(const f16* p, f32x4* a, f32x4* b,
                                                    f32x4* c, f32x4* d) {
    asm volatile("global_load_dwordx4 %0, %4, off sc0 sc1\n\t"
                 "global_load_dwordx4 %1, %5, off sc0 sc1\n\t"
                 "global_load_dwordx4 %2, %6, off sc0 sc1\n\t"
                 "global_load_dwordx4 %3, %7, off sc0 sc1\n\t"
                 "s_waitcnt vmcnt(0)"
                 : "=&v"(*a), "=&v"(*b), "=&v"(*c), "=&v"(*d)
                 : "v"(p), "v"(p + 8), "v"(p + 16), "v"(p + 24) : "memory");
}

// true if no f16 half of the 16B chunk equals the poison pattern
static __device__ __forceinline__ int chunk_clean(f32x4 v) {
#pragma unroll
    for (int i = 0; i < 4; ++i) {
        unsigned u = __float_as_uint(v[i]);
        if ((u & 0xFFFFu) == POISON || (u >> 16) == POISON) return 0;
    }
    return 1;
}

// ---------------- poison init: fill 3 h slots with f16 +inf ----------------
__global__ __launch_bounds__(256)
void k_poison(f16* __restrict__ hsl) {
    f32x4 v;
    const float pf = __uint_as_float((POISON << 16) | POISON);
#pragma unroll
    for (int i = 0; i < 4; ++i) v[i] = pf;
    const size_t i = ((size_t)blockIdx.x * 256 + threadIdx.x) * 8;
    if (i < (size_t)3 * HSZ) *(f32x4*)(hsl + i) = v;
}

// ---------------- transpose: f32 in[512][2048] -> f16 out[2048][512] ----------------
__global__ __launch_bounds__(256)
void k_transpose(const float* __restrict__ in, f16* __restrict__ out) {
    __shared__ f16 tile[64][72];
    const int c0 = blockIdx.x * 64;
    const int r0 = blockIdx.y * 64;
    const int tid = threadIdx.x;
    {
        const int lr = tid >> 2;
        const int lc = (tid & 3) << 4;
        const float* src = in + (size_t)(r0 + lr) * NGATE + c0 + lc;
        float4 v0 = ((const float4*)src)[0];
        float4 v1 = ((const float4*)src)[1];
        float4 v2 = ((const float4*)src)[2];
        float4 v3 = ((const float4*)src)[3];
        *(f16x8*)&tile[lr][lc]     = pack8(v0, v1);
        *(f16x8*)&tile[lr][lc + 8] = pack8(v2, v3);
    }
    __syncthreads();
    {
        const int lc = tid >> 2;
        const int lr = (tid & 3) << 4;
        f16x8 a, b;
#pragma unroll
        for (int i = 0; i < 8; ++i) a[i] = tile[lr + i][lc];
#pragma unroll
        for (int i = 0; i < 8; ++i) b[i] = tile[lr + 8 + i][lc];
        f16* dst = out + (size_t)(c0 + lc) * NKIN + r0 + lr;
        *(f16x8*)dst       = a;
        *(f16x8*)(dst + 8) = b;
    }
}

// ---------------- projection: xz[t][b][g] = x[b][t][:] @ W[:][g] + bias[g] ----------------
__global__ __launch_bounds__(256)
void k_proj(const float* __restrict__ x, const f16* __restrict__ Wt,
            const float* __restrict__ bias, f16* __restrict__ xz) {
    __shared__ f16 As[128][40];
    __shared__ f16 Bs[128][40];
    const int bid = blockIdx.y * gridDim.x + blockIdx.x;   // 0..2047
    const int swz = (bid & 7) * 256 + (bid >> 3);          // XCD-contiguous chunks
    const int nb = swz & 15;
    const int tb = swz >> 4;
    const int n0 = nb * 128;
    const int tid  = threadIdx.x;
    const int lane = tid & 63;
    const int wid  = tid >> 6;
    const int wm = (wid >> 1) * 64;
    const int wn = (wid & 1) * 64;
    const int lm = lane & 15;
    const int lg = lane >> 4;

    f32x4 acc[4][4];
#pragma unroll
    for (int mi = 0; mi < 4; ++mi)
#pragma unroll
        for (int ni = 0; ni < 4; ++ni)
#pragma unroll
            for (int i = 0; i < 4; ++i) acc[mi][ni][i] = 0.0f;

    for (int kt = 0; kt < NKIN; kt += 32) {
        {
            const int brow = tid >> 1;
            const int kq   = (tid & 1) << 4;
            const float* src = x + ((size_t)brow * NTIME + tb) * NKIN + kt + kq;
            float4 v0 = ((const float4*)src)[0];
            float4 v1 = ((const float4*)src)[1];
            float4 v2 = ((const float4*)src)[2];
            float4 v3 = ((const float4*)src)[3];
            *(f16x8*)&As[brow][kq]     = pack8(v0, v1);
            *(f16x8*)&As[brow][kq + 8] = pack8(v2, v3);
        }
        {
            const int nrow = tid >> 1;
            const int kq   = (tid & 1) << 4;
            const f16* src = Wt + (size_t)(n0 + nrow) * NKIN + kt + kq;
            *(f16x8*)&Bs[nrow][kq]     = *(const f16x8*)src;
            *(f16x8*)&Bs[nrow][kq + 8] = *(const f16x8*)(src + 8);
        }
        __syncthreads();
        f16x8 a[4], b[4];
#pragma unroll
        for (int mi = 0; mi < 4; ++mi)
            a[mi] = *(const f16x8*)&As[wm + mi * 16 + lm][lg * 8];
#pragma unroll
        for (int ni = 0; ni < 4; ++ni)
            b[ni] = *(const f16x8*)&Bs[wn + ni * 16 + lm][lg * 8];
#pragma unroll
        for (int mi = 0; mi < 4; ++mi)
#pragma unroll
            for (int ni = 0; ni < 4; ++ni)
                acc[mi][ni] = __builtin_amdgcn_mfma_f32_16x16x32_f16(a[mi], b[ni], acc[mi][ni], 0, 0, 0);
        __syncthreads();
    }
#pragma unroll
    for (int mi = 0; mi < 4; ++mi) {
#pragma unroll
        for (int ni = 0; ni < 4; ++ni) {
            const int col = n0 + wn + ni * 16 + lm;
            const float bv = bias[col];
#pragma unroll
            for (int i = 0; i < 4; ++i) {
                const int brow = wm + mi * 16 + lg * 4 + i;
                xz[((size_t)tb * NBATCH + brow) * NGATE + col] = (f16)(acc[mi][ni][i] + bv);
            }
        }
    }
}

// ---------------- persistent LSTM: U pinned in registers, poll-the-data exchange ----
// 256 blocks = 8 groups (16 batch rows) x 32 slots (16 unit-cols x 4 gates), STATIC.
// grid == #CUs -> 1 block/CU, 1 wave/SIMD -> full VGPR file per wave. U-slice
// (16 B-frags = 64 VGPR) loaded once and made OPAQUE via inline asm so the
// compiler cannot sink the loads back into the loop (r9 failure: VGPR=72,
// FETCH +7MB proved rematerialization). LDS: h rows + gate exchange only.
// h[t] in rotating slot t%3, poison-initialized; consumers poll 16B chunks until
// poison-free (sc0sc1 MALL, proven r8). Depth-3 poison recycle.
__global__ __launch_bounds__(256, 1)
void k_lstm(const f16* __restrict__ xz, const f16* __restrict__ Ut,
            f16* __restrict__ hsl, float* __restrict__ out) {
    __shared__ f16 As[16][512];      // 16 h rows, XOR-swizzled (16KB)
    __shared__ float zs[4][16][17];  // gate exchange (4.25KB)
    const int bid = blockIdx.x;
    const int grp  = bid & 7;        // static batch group
    const int slot = bid >> 3;       // static unit slot 0..31
    const int r0 = grp * GROWS;
    const int u0 = slot * GUNITS;
    const int tid  = threadIdx.x;
    const int lane = tid & 63;
    const int g    = tid >> 6;       // wave id == gate (i,f,g,o)
    const int lm = lane & 15;
    const int lg = lane >> 4;

    // one-time: load this wave's 16 U B-fragments into registers (64 VGPR).
    // B-frag[ks]: lane (lm,lg) holds Ut[g*512 + u0 + lm][ks*32 + lg*8 .. +8]
    f16x8 bu[16];
    {
        const f16* ub = Ut + ((size_t)(g * NUNITS + u0 + lm)) * NUNITS + lg * 8;
#pragma unroll
        for (int ks = 0; ks < 16; ++ks) {
            bu[ks] = *(const f16x8*)(ub + ks * 32);
            asm volatile("" : "+v"(bu[ks]));   // opaque: cannot be rematerialized
        }
    }
    // zero As (t=0 uses h=0)
    {
        f32x4 z = {0.f, 0.f, 0.f, 0.f};
        for (int i = tid; i < 16 * 64; i += 256)
            *(f32x4*)&As[i >> 6][(i & 63) * 8] = z;
    }

    const int srow = tid >> 4;       // 0..15
    const int suu  = tid & 15;       // 0..15
    const int gidx = (r0 + srow) * NUNITS + u0 + suu;
    float c_reg = 0.0f;

    // poison chunk vector
    f32x4 pz;
    {
        const float pf = __uint_as_float((POISON << 16) | POISON);
#pragma unroll
        for (int i = 0; i < 4; ++i) pz[i] = pf;
    }

    // xz prefetch (t=0): px[i] = xz[0][r0+lg*4+i][g*512+u0+lm]
    float px[4];
    {
        const f16* xp = xz + ((size_t)(r0 + lg * 4)) * NGATE + g * NUNITS + u0 + lm;
#pragma unroll
        for (int i = 0; i < 4; ++i) px[i] = (float)xp[(size_t)i * NGATE];
    }
    __syncthreads();   // As zero visible before t=0 MFMA

    for (int t = 0; t < NTIME; ++t) {
        const f16* hin = hsl + (size_t)((t + 2) % 3) * HSZ;   // slot of h[t-1]
        f16*      hout = hsl + (size_t)(t % 3) * HSZ;         // slot of h[t]

        if (t > 0) {
            // poll-stage: spin on own 4 chunks (64B of one h row) until poison-free
            {
                const int row = tid >> 4;
                const int seg = tid & 15;
                const f16* src = hin + (size_t)(r0 + row) * NUNITS + seg * 32;
                f32x4 a, b, c, d;
                for (int spin = 0; spin < 65536; ++spin) {
                    load4x16_sys(src, &a, &b, &c, &d);
                    if (chunk_clean(a) && chunk_clean(b) &&
                        chunk_clean(c) && chunk_clean(d)) break;
                }
                const int c0_ = seg * 4;
                *(f32x4*)&As[row][((c0_ + 0) ^ (row & 7)) * 8] = a;
                *(f32x4*)&As[row][((c0_ + 1) ^ (row & 7)) * 8] = b;
                *(f32x4*)&As[row][((c0_ + 2) ^ (row & 7)) * 8] = c;
                *(f32x4*)&As[row][((c0_ + 3) ^ (row & 7)) * 8] = d;
            }
            __syncthreads();
            // recycle: poison own chunk of slot (t+1)%3 (holds h[t-2]; poll success
            // of h[t-1] proves everyone finished reading it). 32 x 16B.
            if (tid < 32) {
                f16* ps = hsl + (size_t)((t + 1) % 3) * HSZ
                              + (size_t)(r0 + (tid >> 1)) * NUNITS + u0 + (tid & 1) * 8;
                store_16B_sys(ps, pz);
            }
        }

        // MFMA: wave g computes z[16 rows][16 cols] for its gate.
        // B operands pinned in registers; only A (h) from LDS.
        // 4 independent chains (depth 4) hide MFMA latency.
        f32x4 acc0, acc1, acc2, acc3;
#pragma unroll
        for (int i = 0; i < 4; ++i) {
            acc0[i] = px[i]; acc1[i] = 0.f; acc2[i] = 0.f; acc3[i] = 0.f;
        }
#pragma unroll
        for (int ks = 0; ks < 16; ks += 4) {
            const int ca0 = (((ks + 0) * 4 + lg) ^ (lm & 7)) * 8;
            const int ca1 = (((ks + 1) * 4 + lg) ^ (lm & 7)) * 8;
            const int ca2 = (((ks + 2) * 4 + lg) ^ (lm & 7)) * 8;
            const int ca3 = (((ks + 3) * 4 + lg) ^ (lm & 7)) * 8;
            f16x8 a0 = *(const f16x8*)&As[lm][ca0];
            f16x8 a1 = *(const f16x8*)&As[lm][ca1];
            f16x8 a2 = *(const f16x8*)&As[lm][ca2];
            f16x8 a3 = *(const f16x8*)&As[lm][ca3];
            acc0 = __builtin_amdgcn_mfma_f32_16x16x32_f16(a0, bu[ks + 0], acc0, 0, 0, 0);
            acc1 = __builtin_amdgcn_mfma_f32_16x16x32_f16(a1, bu[ks + 1], acc1, 0, 0, 0);
            acc2 = __builtin_amdgcn_mfma_f32_16x16x32_f16(a2, bu[ks + 2], acc2, 0, 0, 0);
            acc3 = __builtin_amdgcn_mfma_f32_16x16x32_f16(a3, bu[ks + 3], acc3, 0, 0, 0);
        }
        f32x4 acc = (acc0 + acc1) + (acc2 + acc3);

        // prefetch next step's xz (plain cached loads; overlaps rest of step)
        if (t + 1 < NTIME) {
            const f16* xp = xz + ((size_t)(t + 1) * NBATCH + r0 + lg * 4) * NGATE
                               + g * NUNITS + u0 + lm;
#pragma unroll
            for (int i = 0; i < 4; ++i) px[i] = (float)xp[(size_t)i * NGATE];
        }

        // gate exchange: lane (lm,lg) reg i holds z[lg*4+i][lm]
#pragma unroll
        for (int i = 0; i < 4; ++i)
            zs[g][lg * 4 + i][lm] = acc[i];
        __syncthreads();

        // state update: 256 threads = 16 rows x 16 units
        const float zi = zs[0][srow][suu];
        const float zf = zs[1][srow][suu];
        const float zg = zs[2][srow][suu];
        const float zo = zs[3][srow][suu];
        const float iv = sigmoidf_(zi);
        const float fv = sigmoidf_(zf);
        const float gv = tanhf_(zg);
        const float ov = sigmoidf_(zo);
        c_reg = fv * c_reg + iv * gv;
        const float hn = ov * tanhf_(c_reg);

        if (t == NTIME - 1) {
            out[gidx]          = hn;
            out[65536 + gidx]  = hn;
            out[131072 + gidx] = c_reg;
        } else {
            // fire-and-forget h store (wave-coalesced 2B sc0sc1); consumers
            // poll the data itself, so no drain / no flag needed
            union { f16 h; unsigned short u; } cv; cv.h = (f16)hn;
            store_u16_sys(hout + gidx, cv.u);
        }
    }
}

extern "C" void kernel_launch(void* const* d_in, const int* in_sizes, int n_in,
                              void* d_out, int out_size, void* d_ws, size_t ws_size,
                              hipStream_t stream) {
    const float* x    = (const float*)d_in[0];
    const float* W    = (const float*)d_in[1];
    const float* U    = (const float*)d_in[2];
    const float* bias = (const float*)d_in[3];
    float* out = (float*)d_out;
    char* ws = (char*)d_ws;

    size_t off = 0;
    f16* Wt = (f16*)(ws + off); off += (size_t)NGATE * NKIN * 2;
    f16* Ut = (f16*)(ws + off); off += (size_t)NGATE * NUNITS * 2;
    f16* xz = (f16*)(ws + off); off += (size_t)NTIME * NBATCH * NGATE * 2;  // [t][b][g]
    f16* hsl = (f16*)(ws + off); off += (size_t)3 * HSZ * 2;                // 3 h slots
    if (ws_size < off) return;

    k_poison<<<dim3(96), 256, 0, stream>>>(hsl);
    k_transpose<<<dim3(32, 8), 256, 0, stream>>>(W, Wt);
    k_transpose<<<dim3(32, 8), 256, 0, stream>>>(U, Ut);
    k_proj<<<dim3(16, 128), 256, 0, stream>>>(x, Wt, bias, xz);
    k_lstm<<<dim3(256), 256, 0, stream>>>(xz, Ut, hsl, out);
}